// Round 21
// baseline (239.663 us; speedup 1.0000x reference)
//
#include <hip/hip_runtime.h>
#include <math.h>

#define NB 16
#define LL 512
#define CIN 32
#define DM 128
#define DS 16
#define DI 256
#define DTR 8
#define NCOL 3072
#define KTOT 65536
#define ROWS 8192
#define CH 64            // scan chunks (scan1/scan2 granularity)
#define CLEN 8           // steps per scan1 chunk
#define CL3 16           // steps per scan3 chunk (2 scan1-chunks)
#define RB 16            // rows per mega1 block
#define RS 19            // staged rows (RB + 3 conv halo)
#define KC 512           // k_final k-chunk
#define KS 128           // k_final splits
#define OUTSZ 49152

typedef float f32x2 __attribute__((ext_vector_type(2)));

// Hardware-rate transcendentals (v_exp/v_log/v_rcp).
__device__ __forceinline__ float fexp_(float x){ return __expf(x); }
__device__ __forceinline__ float sigmoidf_(float x){
  return __builtin_amdgcn_rcpf(1.f + __expf(-x));
}
__device__ __forceinline__ float softplusf_(float x){
  return (x > 20.f) ? x : __logf(1.f + __expf(x));
}

// MEGA front-end v2 (byte-identical to R19).
__global__ void __launch_bounds__(256) k_mega1(
    const float* __restrict__ x, const float* __restrict__ W_in,
    const float* __restrict__ b_in, const float* __restrict__ W_ip,
    const float* __restrict__ cw, const float* __restrict__ cb,
    const float* __restrict__ W_xp, const float* __restrict__ Wdt,
    const float* __restrict__ bdt, const float* __restrict__ A_log,
    float* __restrict__ u, float* __restrict__ z,
    float* __restrict__ xdbc, float* __restrict__ Hc, float* __restrict__ Sdt) {
  __shared__ float xs[RS][32];
  __shared__ float hs[RS][128];
  __shared__ float up[RS][256];
  __shared__ float ul[RB][256];
  __shared__ float xl[RB][40];
  int t = threadIdx.x;
  int b  = blockIdx.x >> 5;
  int lt = blockIdx.x & 31;
  int l0 = lt * RB;
  int row0 = (b<<9) + l0;
  for (int i=t; i<RS*32; i+=256) {
    int r = i >> 5, c = i & 31;
    int li = l0 - 3 + r;
    xs[r][c] = (li >= 0) ? x[((b<<9)+li)*CIN + c] : 0.f;
  }
  __syncthreads();
  for (int i=t; i<RS*128; i+=256) {
    int r = i >> 7, c = i & 127;
    float acc = b_in[c];
    #pragma unroll
    for (int k=0;k<CIN;k++) acc = fmaf(xs[r][k], W_in[k*DM+c], acc);
    hs[r][c] = acc;
  }
  __syncthreads();
  {
    int lane = t & 127;
    int rgrp = t >> 7;
    int c0 = lane * 4;
    if (c0 < 256) {
      int r0 = rgrp * 9;
      float acc[10][4] = {};
      for (int k4=0;k4<32;k4++) {
        float ha[10][4];
        #pragma unroll
        for (int i=0;i<10;i++) {
          float4 v = *(const float4*)&hs[r0+i][k4*4];
          ha[i][0]=v.x; ha[i][1]=v.y; ha[i][2]=v.z; ha[i][3]=v.w;
        }
        #pragma unroll
        for (int j=0;j<4;j++) {
          float4 w = *(const float4*)(W_ip + (k4*4+j)*512 + c0);
          #pragma unroll
          for (int i=0;i<10;i++) {
            acc[i][0]=fmaf(ha[i][j],w.x,acc[i][0]);
            acc[i][1]=fmaf(ha[i][j],w.y,acc[i][1]);
            acc[i][2]=fmaf(ha[i][j],w.z,acc[i][2]);
            acc[i][3]=fmaf(ha[i][j],w.w,acc[i][3]);
          }
        }
      }
      #pragma unroll
      for (int i=0;i<10;i++)
        *(float4*)&up[r0+i][c0] = make_float4(acc[i][0],acc[i][1],acc[i][2],acc[i][3]);
    } else {
      int r0z = rgrp * 8;
      float acc[8][4] = {};
      for (int k4=0;k4<32;k4++) {
        float ha[8][4];
        #pragma unroll
        for (int i=0;i<8;i++) {
          float4 v = *(const float4*)&hs[3+r0z+i][k4*4];
          ha[i][0]=v.x; ha[i][1]=v.y; ha[i][2]=v.z; ha[i][3]=v.w;
        }
        #pragma unroll
        for (int j=0;j<4;j++) {
          float4 w = *(const float4*)(W_ip + (k4*4+j)*512 + c0);
          #pragma unroll
          for (int i=0;i<8;i++) {
            acc[i][0]=fmaf(ha[i][j],w.x,acc[i][0]);
            acc[i][1]=fmaf(ha[i][j],w.y,acc[i][1]);
            acc[i][2]=fmaf(ha[i][j],w.z,acc[i][2]);
            acc[i][3]=fmaf(ha[i][j],w.w,acc[i][3]);
          }
        }
      }
      #pragma unroll
      for (int i=0;i<8;i++)
        *(float4*)(z + (row0+r0z+i)*DI + (c0-256)) =
          make_float4(acc[i][0],acc[i][1],acc[i][2],acc[i][3]);
    }
  }
  __syncthreads();
  for (int i=t; i<RB*256; i+=256) {
    int r = i >> 8, d = i & 255;
    float s = cb[d];
    #pragma unroll
    for (int j=0;j<4;j++) {
      int li = l0 + r - 3 + j;
      if (li >= 0) s = fmaf(cw[d*4+j], up[r+j][d], s);
    }
    float uv = s * sigmoidf_(s);
    ul[r][d] = uv;
    u[(row0+r)*DI + d] = uv;
  }
  __syncthreads();
  for (int i=t; i<RB*40; i+=256) {
    int r = i / 40, cc = i - r*40;
    float acc = 0.f;
    #pragma unroll 8
    for (int k4=0;k4<64;k4++) {
      float4 uv = *(const float4*)&ul[r][k4*4];
      acc = fmaf(uv.x, W_xp[(k4*4+0)*40+cc], acc);
      acc = fmaf(uv.y, W_xp[(k4*4+1)*40+cc], acc);
      acc = fmaf(uv.z, W_xp[(k4*4+2)*40+cc], acc);
      acc = fmaf(uv.w, W_xp[(k4*4+3)*40+cc], acc);
    }
    xl[r][cc] = acc;
    xdbc[row0*40 + i] = acc;
  }
  __syncthreads();
  {
    int d = t;
    float A[16];
    #pragma unroll
    for (int n=0;n<16;n++) A[n] = -fexp_(A_log[d*16+n]);
    float wdt[DTR];
    #pragma unroll
    for (int j=0;j<DTR;j++) wdt[j] = Wdt[j*DI+d];
    float bdtv = bdt[d];
    for (int cc=0; cc<2; ++cc) {
      int cg = lt*2 + cc;
      float hsv[16];
      #pragma unroll
      for (int n=0;n<16;n++) hsv[n] = 0.f;
      float sdt = 0.f;
      for (int l=0;l<CLEN;++l) {
        int rr = cc*CLEN + l;
        float acc = bdtv;
        #pragma unroll
        for (int j=0;j<DTR;j++) acc = fmaf(xl[rr][j], wdt[j], acc);
        float dtv = softplusf_(acc);
        sdt += dtv;
        float du = dtv * ul[rr][d];
        #pragma unroll
        for (int n=0;n<16;n++) {
          float a = fexp_(dtv*A[n]);
          hsv[n] = fmaf(a, hsv[n], du * xl[rr][DTR+n]);
        }
      }
      int hbase = ((b*CH + cg)*DS)*DI + d;
      #pragma unroll
      for (int n=0;n<16;n++) Hc[hbase + n*DI] = hsv[n];
      Sdt[(b*CH + cg)*DI + d] = sdt;
    }
  }
}

// pass 2: block = (b,n), thread = d. (unchanged)
__global__ void k_scan2(const float* __restrict__ A_log, const float* __restrict__ Hc,
                        const float* __restrict__ Sdt, float* __restrict__ Hst) {
  int d = threadIdx.x;
  int b = blockIdx.x >> 4, n = blockIdx.x & 15;
  float A = -fexp_(A_log[d*16+n]);
  float hs = 0.f;
  for (int c=0;c<CH;c++) {
    int off = ((b*CH + c)*DS + n)*DI + d;
    Hst[off] = hs;
    float sdt = Sdt[(b*CH + c)*DI + d];
    hs = fmaf(fexp_(A*sdt), hs, Hc[off]);
  }
}

// pass 3 v2: 16-row chunks (512 blocks). Replays from Hst of even chunk 2c.
// Halves W_out re-reads and per-element stage/barrier overhead vs 8-row.
__global__ void __launch_bounds__(256) k_scan3(
    const float* __restrict__ u, const float* __restrict__ z,
    const float* __restrict__ xdbc, const float* __restrict__ Wdt,
    const float* __restrict__ bdt, const float* __restrict__ A_log,
    const float* __restrict__ Dp, const float* __restrict__ Hst,
    const float* __restrict__ W_out, float* __restrict__ mo) {
  __shared__ float ym[CL3][256];
  __shared__ float xl[CL3][40];
  int t = threadIdx.x;
  int b = blockIdx.x >> 5, c = blockIdx.x & 31, d = t;
  int l0 = c * CL3;
  int row0 = (b<<9) + l0;
  for (int i=t; i<CL3*40; i+=256) xl[i/40][i%40] = xdbc[row0*40 + i];
  __syncthreads();
  int hbase = ((b*CH + 2*c)*DS)*DI + d;   // start state of even chunk 2c
  float A[16], hsv[16];
  #pragma unroll
  for (int n=0;n<16;n++){ A[n] = -fexp_(A_log[d*16+n]); hsv[n] = Hst[hbase + n*DI]; }
  float wdt[DTR];
  #pragma unroll
  for (int j=0;j<DTR;j++) wdt[j] = Wdt[j*DI+d];
  float bdtv = bdt[d];
  float Dv = Dp[d];
  for (int l=0;l<CL3;++l) {
    int row = row0 + l;
    float acc = bdtv;
    #pragma unroll
    for (int j=0;j<DTR;j++) acc = fmaf(xl[l][j], wdt[j], acc);
    float dtv = softplusf_(acc);
    float uv = u[(row<<8) + d];
    float zv = z[(row<<8) + d];
    float du = dtv * uv;
    float y = 0.f;
    #pragma unroll
    for (int n=0;n<16;n++) {
      float a = fexp_(dtv*A[n]);
      hsv[n] = fmaf(a, hsv[n], du * xl[l][DTR+n]);
      y = fmaf(hsv[n], xl[l][DTR+DS+n], y);
    }
    y = fmaf(uv, Dv, y);
    ym[l][d] = y * (zv * sigmoidf_(zv));
  }
  __syncthreads();
  // mo = ym @ W_out for the 16 rows: thread = (col cc, 8-row group)
  int cc = t & 127;
  int rg = (t >> 7) * 8;
  float acc[8] = {};
  for (int k4=0;k4<64;k4++) {
    float w0 = W_out[(k4*4+0)*DM+cc];
    float w1 = W_out[(k4*4+1)*DM+cc];
    float w2 = W_out[(k4*4+2)*DM+cc];
    float w3 = W_out[(k4*4+3)*DM+cc];
    #pragma unroll
    for (int o=0;o<8;o++) {
      float4 yv = *(const float4*)&ym[rg+o][k4*4];
      acc[o] = fmaf(yv.w, w3, fmaf(yv.z, w2, fmaf(yv.y, w1, fmaf(yv.x, w0, acc[o]))));
    }
  }
  #pragma unroll
  for (int o=0;o<8;o++) mo[(row0+rg+o)*DM + cc] = acc[o];
}

// final (proven at-floor, unchanged)
__global__ void __launch_bounds__(256) k_final(
    const float* __restrict__ flat, const float* __restrict__ W,
    float* __restrict__ part) {
  __shared__ float lds[KC][16];
  int t = threadIdx.x;
  int n0 = blockIdx.x * 512;
  int k0 = blockIdx.y * KC;
  for (int i = t; i < 16*(KC/4); i += 256) {
    int bb  = i & 15;
    int kk4 = i >> 4;
    float4 v = *(const float4*)(flat + bb*KTOT + k0 + kk4*4);
    lds[kk4*4+0][bb] = v.x; lds[kk4*4+1][bb] = v.y;
    lds[kk4*4+2][bb] = v.z; lds[kk4*4+3][bb] = v.w;
  }
  __syncthreads();
  int c0 = n0 + t*2;
  float2 acc[16];
  #pragma unroll
  for (int b=0;b<16;b++) acc[b] = make_float2(0.f,0.f);
  const float* Wp = W + (size_t)k0*NCOL + c0;
  for (int kk=0; kk<KC; kk+=4) {
    f32x2 w0 = __builtin_nontemporal_load((const f32x2*)(Wp + (size_t)(kk+0)*NCOL));
    f32x2 w1 = __builtin_nontemporal_load((const f32x2*)(Wp + (size_t)(kk+1)*NCOL));
    f32x2 w2 = __builtin_nontemporal_load((const f32x2*)(Wp + (size_t)(kk+2)*NCOL));
    f32x2 w3 = __builtin_nontemporal_load((const f32x2*)(Wp + (size_t)(kk+3)*NCOL));
    const float4* f0 = (const float4*)&lds[kk+0][0];
    const float4* f1 = (const float4*)&lds[kk+1][0];
    const float4* f2 = (const float4*)&lds[kk+2][0];
    const float4* f3 = (const float4*)&lds[kk+3][0];
    #pragma unroll
    for (int q=0;q<4;q++) {
      float4 fa = f0[q], fb = f1[q], fc = f2[q], fd = f3[q];
      float fs0[4] = {fa.x,fa.y,fa.z,fa.w};
      float fs1[4] = {fb.x,fb.y,fb.z,fb.w};
      float fs2[4] = {fc.x,fc.y,fc.z,fc.w};
      float fs3[4] = {fd.x,fd.y,fd.z,fd.w};
      #pragma unroll
      for (int j=0;j<4;j++) {
        int b = q*4+j;
        acc[b].x=fmaf(fs0[j],w0.x,acc[b].x); acc[b].y=fmaf(fs0[j],w0.y,acc[b].y);
        acc[b].x=fmaf(fs1[j],w1.x,acc[b].x); acc[b].y=fmaf(fs1[j],w1.y,acc[b].y);
        acc[b].x=fmaf(fs2[j],w2.x,acc[b].x); acc[b].y=fmaf(fs2[j],w2.y,acc[b].y);
        acc[b].x=fmaf(fs3[j],w3.x,acc[b].x); acc[b].y=fmaf(fs3[j],w3.y,acc[b].y);
      }
    }
  }
  float* p = part + (size_t)blockIdx.y*OUTSZ;
  #pragma unroll
  for (int b=0;b<16;b++) {
    f32x2 v; v.x = acc[b].x; v.y = acc[b].y;
    __builtin_nontemporal_store(v, (f32x2*)(p + b*NCOL + c0));
  }
}

// out = sum_s part[s] + bias (unchanged)
__global__ void k_reduce(const float* __restrict__ part, const float* __restrict__ bias,
                         float* __restrict__ out) {
  int idx = blockIdx.x*256 + threadIdx.x;
  float acc = bias[idx % NCOL];
  #pragma unroll 8
  for (int s=0;s<KS;s++)
    acc += __builtin_nontemporal_load(part + (size_t)s*OUTSZ + idx);
  out[idx] = acc;
}

extern "C" void kernel_launch(void* const* d_in, const int* in_sizes, int n_in,
                              void* d_out, int out_size, void* d_ws, size_t ws_size,
                              hipStream_t stream) {
  const float* x        = (const float*)d_in[0];
  const float* W_in     = (const float*)d_in[1];
  const float* b_in     = (const float*)d_in[2];
  const float* W_inproj = (const float*)d_in[3];
  const float* conv_w   = (const float*)d_in[4];
  const float* conv_b   = (const float*)d_in[5];
  const float* W_xproj  = (const float*)d_in[6];
  const float* W_dt     = (const float*)d_in[7];
  const float* b_dt     = (const float*)d_in[8];
  const float* A_log    = (const float*)d_in[9];
  const float* Dp       = (const float*)d_in[10];
  const float* W_out    = (const float*)d_in[11];
  const float* W_outproj= (const float*)d_in[12];
  const float* b_outproj= (const float*)d_in[13];
  float* out = (float*)d_out;
  float* ws  = (float*)d_ws;

  float* u    = ws;             // 2097152
  float* z    = ws + 2097152;   // 2097152
  float* xdbc = ws + 4194304;   // 327680
  float* Hc   = ws + 4521984;   // 4194304
  float* Sdt  = ws + 8716288;   // 262144
  float* Hst  = ws + 8978432;   // 4194304
  float* mo   = ws + 13172736;  // 1048576
  float* part = ws + 14221312;  // 6291456 -> total ~82 MB

  k_mega1 <<<512,  256, 0, stream>>>(x, W_in, b_in, W_inproj, conv_w, conv_b,
                                     W_xproj, W_dt, b_dt, A_log,
                                     u, z, xdbc, Hc, Sdt);
  k_scan2 <<<256,  256, 0, stream>>>(A_log, Hc, Sdt, Hst);
  k_scan3 <<<512,  256, 0, stream>>>(u, z, xdbc, W_dt, b_dt, A_log, Dp, Hst, W_out, mo);
  k_final <<<dim3(6, KS), 256, 0, stream>>>(mo, W_outproj, part);
  k_reduce<<<192,  256, 0, stream>>>(part, b_outproj, out);
}

// Round 22
// 232.439 us; speedup vs baseline: 1.0311x; 1.0311x over previous
//
#include <hip/hip_runtime.h>
#include <math.h>

#define NB 16
#define LL 512
#define CIN 32
#define DM 128
#define DS 16
#define DI 256
#define DTR 8
#define NCOL 3072
#define KTOT 65536
#define ROWS 8192
#define CH 64            // scan chunks (scan1/scan2 granularity)
#define CLEN 8           // steps per scan1 chunk
#define CL3 16           // steps per scan3 chunk
#define RB 16            // rows per mega1 block
#define RS 19            // staged rows (RB + 3 conv halo)
#define KC 512           // k_final k-chunk
#define KS 128           // k_final splits
#define OUTSZ 49152

typedef float f32x2 __attribute__((ext_vector_type(2)));

// Hardware-rate transcendentals (v_exp/v_log/v_rcp).
__device__ __forceinline__ float fexp_(float x){ return __expf(x); }
__device__ __forceinline__ float sigmoidf_(float x){
  return __builtin_amdgcn_rcpf(1.f + __expf(-x));
}
__device__ __forceinline__ float softplusf_(float x){
  return (x > 20.f) ? x : __logf(1.f + __expf(x));
}

// Precompute W_comb = W_in @ W_inproj (32x512) and bias_comb = b_in @ W_inproj
// (row 32). Exact algebraic fold: xz = x@W_comb + bias_comb.
__global__ void k_comb(const float* __restrict__ W_in, const float* __restrict__ b_in,
                       const float* __restrict__ W_ip, float* __restrict__ Wc) {
  int idx = blockIdx.x*256 + threadIdx.x;   // 33*512 = 16896
  if (idx >= 33*512) return;
  int r = idx >> 9;
  int c = idx & 511;
  float acc = 0.f;
  if (r < 32) {
    #pragma unroll 8
    for (int k=0;k<DM;k++) acc = fmaf(W_in[r*DM + k], W_ip[k*512 + c], acc);
  } else {
    #pragma unroll 8
    for (int k=0;k<DM;k++) acc = fmaf(b_in[k], W_ip[k*512 + c], acc);
  }
  Wc[idx] = acc;
}

// MEGA front-end v3: single K=32 GEMM (x @ W_comb) replaces h + xz GEMMs.
// Then conv+silu, xdbc, chunk-local scan (all identical to R21).
__global__ void __launch_bounds__(256) k_mega1(
    const float* __restrict__ x, const float* __restrict__ Wc,
    const float* __restrict__ cw, const float* __restrict__ cb,
    const float* __restrict__ W_xp, const float* __restrict__ Wdt,
    const float* __restrict__ bdt, const float* __restrict__ A_log,
    float* __restrict__ u, float* __restrict__ z,
    float* __restrict__ xdbc, float* __restrict__ Hc, float* __restrict__ Sdt) {
  __shared__ float xs[RS][32];
  __shared__ float up[RS][256];
  __shared__ float ul[RB][256];
  __shared__ float xl[RB][40];
  int t = threadIdx.x;
  int b  = blockIdx.x >> 5;
  int lt = blockIdx.x & 31;
  int l0 = lt * RB;
  int row0 = (b<<9) + l0;
  // stage x rows l0-3 .. l0+15 (zero for li<0; conv guard makes halo values moot)
  for (int i=t; i<RS*32; i+=256) {
    int r = i >> 5, c = i & 31;
    int li = l0 - 3 + r;
    xs[r][c] = (li >= 0) ? x[((b<<9)+li)*CIN + c] : 0.f;
  }
  __syncthreads();
  // merged xz GEMM from xs: K=32. 128 col-lanes x 2 row-groups, wave-uniform roles.
  {
    int lane = t & 127;
    int rgrp = t >> 7;
    int c0 = lane * 4;
    float4 bc = *(const float4*)(Wc + 32*512 + c0);
    if (c0 < 256) {                  // u_pre: rows rgrp*9 .. rgrp*9+9
      int r0 = rgrp * 9;
      float acc[10][4];
      #pragma unroll
      for (int i=0;i<10;i++){ acc[i][0]=bc.x; acc[i][1]=bc.y; acc[i][2]=bc.z; acc[i][3]=bc.w; }
      #pragma unroll
      for (int k4=0;k4<8;k4++) {
        float ha[10][4];
        #pragma unroll
        for (int i=0;i<10;i++) {
          float4 v = *(const float4*)&xs[r0+i][k4*4];
          ha[i][0]=v.x; ha[i][1]=v.y; ha[i][2]=v.z; ha[i][3]=v.w;
        }
        #pragma unroll
        for (int j=0;j<4;j++) {
          float4 w = *(const float4*)(Wc + (k4*4+j)*512 + c0);
          #pragma unroll
          for (int i=0;i<10;i++) {
            acc[i][0]=fmaf(ha[i][j],w.x,acc[i][0]);
            acc[i][1]=fmaf(ha[i][j],w.y,acc[i][1]);
            acc[i][2]=fmaf(ha[i][j],w.z,acc[i][2]);
            acc[i][3]=fmaf(ha[i][j],w.w,acc[i][3]);
          }
        }
      }
      #pragma unroll
      for (int i=0;i<10;i++)
        *(float4*)&up[r0+i][c0] = make_float4(acc[i][0],acc[i][1],acc[i][2],acc[i][3]);
    } else {                         // z: rows rgrp*8 .. +7 (row rz uses xs[3+rz])
      int r0z = rgrp * 8;
      float acc[8][4];
      #pragma unroll
      for (int i=0;i<8;i++){ acc[i][0]=bc.x; acc[i][1]=bc.y; acc[i][2]=bc.z; acc[i][3]=bc.w; }
      #pragma unroll
      for (int k4=0;k4<8;k4++) {
        float ha[8][4];
        #pragma unroll
        for (int i=0;i<8;i++) {
          float4 v = *(const float4*)&xs[3+r0z+i][k4*4];
          ha[i][0]=v.x; ha[i][1]=v.y; ha[i][2]=v.z; ha[i][3]=v.w;
        }
        #pragma unroll
        for (int j=0;j<4;j++) {
          float4 w = *(const float4*)(Wc + (k4*4+j)*512 + c0);
          #pragma unroll
          for (int i=0;i<8;i++) {
            acc[i][0]=fmaf(ha[i][j],w.x,acc[i][0]);
            acc[i][1]=fmaf(ha[i][j],w.y,acc[i][1]);
            acc[i][2]=fmaf(ha[i][j],w.z,acc[i][2]);
            acc[i][3]=fmaf(ha[i][j],w.w,acc[i][3]);
          }
        }
      }
      #pragma unroll
      for (int i=0;i<8;i++)
        *(float4*)(z + (row0+r0z+i)*DI + (c0-256)) =
          make_float4(acc[i][0],acc[i][1],acc[i][2],acc[i][3]);
    }
  }
  __syncthreads();
  // conv + silu -> ul (LDS) + u (global)
  for (int i=t; i<RB*256; i+=256) {
    int r = i >> 8, d = i & 255;
    float s = cb[d];
    #pragma unroll
    for (int j=0;j<4;j++) {
      int li = l0 + r - 3 + j;
      if (li >= 0) s = fmaf(cw[d*4+j], up[r+j][d], s);
    }
    float uv = s * sigmoidf_(s);
    ul[r][d] = uv;
    u[(row0+r)*DI + d] = uv;
  }
  __syncthreads();
  // xdbc rows (16 x 40) from LDS u
  for (int i=t; i<RB*40; i+=256) {
    int r = i / 40, cc = i - r*40;
    float acc = 0.f;
    #pragma unroll 8
    for (int k4=0;k4<64;k4++) {
      float4 uv = *(const float4*)&ul[r][k4*4];
      acc = fmaf(uv.x, W_xp[(k4*4+0)*40+cc], acc);
      acc = fmaf(uv.y, W_xp[(k4*4+1)*40+cc], acc);
      acc = fmaf(uv.z, W_xp[(k4*4+2)*40+cc], acc);
      acc = fmaf(uv.w, W_xp[(k4*4+3)*40+cc], acc);
    }
    xl[r][cc] = acc;
    xdbc[row0*40 + i] = acc;
  }
  __syncthreads();
  // chunk-local scans: 2 chunks (8 steps each).
  {
    int d = t;
    float A[16];
    #pragma unroll
    for (int n=0;n<16;n++) A[n] = -fexp_(A_log[d*16+n]);
    float wdt[DTR];
    #pragma unroll
    for (int j=0;j<DTR;j++) wdt[j] = Wdt[j*DI+d];
    float bdtv = bdt[d];
    for (int cc=0; cc<2; ++cc) {
      int cg = lt*2 + cc;
      float hsv[16];
      #pragma unroll
      for (int n=0;n<16;n++) hsv[n] = 0.f;
      float sdt = 0.f;
      for (int l=0;l<CLEN;++l) {
        int rr = cc*CLEN + l;
        float acc = bdtv;
        #pragma unroll
        for (int j=0;j<DTR;j++) acc = fmaf(xl[rr][j], wdt[j], acc);
        float dtv = softplusf_(acc);
        sdt += dtv;
        float du = dtv * ul[rr][d];
        #pragma unroll
        for (int n=0;n<16;n++) {
          float a = fexp_(dtv*A[n]);
          hsv[n] = fmaf(a, hsv[n], du * xl[rr][DTR+n]);
        }
      }
      int hbase = ((b*CH + cg)*DS)*DI + d;
      #pragma unroll
      for (int n=0;n<16;n++) Hc[hbase + n*DI] = hsv[n];
      Sdt[(b*CH + cg)*DI + d] = sdt;
    }
  }
}

// pass 2: block = (b,n), thread = d. (unchanged)
__global__ void k_scan2(const float* __restrict__ A_log, const float* __restrict__ Hc,
                        const float* __restrict__ Sdt, float* __restrict__ Hst) {
  int d = threadIdx.x;
  int b = blockIdx.x >> 4, n = blockIdx.x & 15;
  float A = -fexp_(A_log[d*16+n]);
  float hs = 0.f;
  for (int c=0;c<CH;c++) {
    int off = ((b*CH + c)*DS + n)*DI + d;
    Hst[off] = hs;
    float sdt = Sdt[(b*CH + c)*DI + d];
    hs = fmaf(fexp_(A*sdt), hs, Hc[off]);
  }
}

// pass 3: 16-row chunks from Hst of even chunk 2c; fused mo = ym@W_out. (unchanged)
__global__ void __launch_bounds__(256) k_scan3(
    const float* __restrict__ u, const float* __restrict__ z,
    const float* __restrict__ xdbc, const float* __restrict__ Wdt,
    const float* __restrict__ bdt, const float* __restrict__ A_log,
    const float* __restrict__ Dp, const float* __restrict__ Hst,
    const float* __restrict__ W_out, float* __restrict__ mo) {
  __shared__ float ym[CL3][256];
  __shared__ float xl[CL3][40];
  int t = threadIdx.x;
  int b = blockIdx.x >> 5, c = blockIdx.x & 31, d = t;
  int l0 = c * CL3;
  int row0 = (b<<9) + l0;
  for (int i=t; i<CL3*40; i+=256) xl[i/40][i%40] = xdbc[row0*40 + i];
  __syncthreads();
  int hbase = ((b*CH + 2*c)*DS)*DI + d;
  float A[16], hsv[16];
  #pragma unroll
  for (int n=0;n<16;n++){ A[n] = -fexp_(A_log[d*16+n]); hsv[n] = Hst[hbase + n*DI]; }
  float wdt[DTR];
  #pragma unroll
  for (int j=0;j<DTR;j++) wdt[j] = Wdt[j*DI+d];
  float bdtv = bdt[d];
  float Dv = Dp[d];
  for (int l=0;l<CL3;++l) {
    int row = row0 + l;
    float acc = bdtv;
    #pragma unroll
    for (int j=0;j<DTR;j++) acc = fmaf(xl[l][j], wdt[j], acc);
    float dtv = softplusf_(acc);
    float uv = u[(row<<8) + d];
    float zv = z[(row<<8) + d];
    float du = dtv * uv;
    float y = 0.f;
    #pragma unroll
    for (int n=0;n<16;n++) {
      float a = fexp_(dtv*A[n]);
      hsv[n] = fmaf(a, hsv[n], du * xl[l][DTR+n]);
      y = fmaf(hsv[n], xl[l][DTR+DS+n], y);
    }
    y = fmaf(uv, Dv, y);
    ym[l][d] = y * (zv * sigmoidf_(zv));
  }
  __syncthreads();
  int cc = t & 127;
  int rg = (t >> 7) * 8;
  float acc[8] = {};
  for (int k4=0;k4<64;k4++) {
    float w0 = W_out[(k4*4+0)*DM+cc];
    float w1 = W_out[(k4*4+1)*DM+cc];
    float w2 = W_out[(k4*4+2)*DM+cc];
    float w3 = W_out[(k4*4+3)*DM+cc];
    #pragma unroll
    for (int o=0;o<8;o++) {
      float4 yv = *(const float4*)&ym[rg+o][k4*4];
      acc[o] = fmaf(yv.w, w3, fmaf(yv.z, w2, fmaf(yv.y, w1, fmaf(yv.x, w0, acc[o]))));
    }
  }
  #pragma unroll
  for (int o=0;o<8;o++) mo[(row0+rg+o)*DM + cc] = acc[o];
}

// final (proven at-floor, unchanged)
__global__ void __launch_bounds__(256) k_final(
    const float* __restrict__ flat, const float* __restrict__ W,
    float* __restrict__ part) {
  __shared__ float lds[KC][16];
  int t = threadIdx.x;
  int n0 = blockIdx.x * 512;
  int k0 = blockIdx.y * KC;
  for (int i = t; i < 16*(KC/4); i += 256) {
    int bb  = i & 15;
    int kk4 = i >> 4;
    float4 v = *(const float4*)(flat + bb*KTOT + k0 + kk4*4);
    lds[kk4*4+0][bb] = v.x; lds[kk4*4+1][bb] = v.y;
    lds[kk4*4+2][bb] = v.z; lds[kk4*4+3][bb] = v.w;
  }
  __syncthreads();
  int c0 = n0 + t*2;
  float2 acc[16];
  #pragma unroll
  for (int b=0;b<16;b++) acc[b] = make_float2(0.f,0.f);
  const float* Wp = W + (size_t)k0*NCOL + c0;
  for (int kk=0; kk<KC; kk+=4) {
    f32x2 w0 = __builtin_nontemporal_load((const f32x2*)(Wp + (size_t)(kk+0)*NCOL));
    f32x2 w1 = __builtin_nontemporal_load((const f32x2*)(Wp + (size_t)(kk+1)*NCOL));
    f32x2 w2 = __builtin_nontemporal_load((const f32x2*)(Wp + (size_t)(kk+2)*NCOL));
    f32x2 w3 = __builtin_nontemporal_load((const f32x2*)(Wp + (size_t)(kk+3)*NCOL));
    const float4* f0 = (const float4*)&lds[kk+0][0];
    const float4* f1 = (const float4*)&lds[kk+1][0];
    const float4* f2 = (const float4*)&lds[kk+2][0];
    const float4* f3 = (const float4*)&lds[kk+3][0];
    #pragma unroll
    for (int q=0;q<4;q++) {
      float4 fa = f0[q], fb = f1[q], fc = f2[q], fd = f3[q];
      float fs0[4] = {fa.x,fa.y,fa.z,fa.w};
      float fs1[4] = {fb.x,fb.y,fb.z,fb.w};
      float fs2[4] = {fc.x,fc.y,fc.z,fc.w};
      float fs3[4] = {fd.x,fd.y,fd.z,fd.w};
      #pragma unroll
      for (int j=0;j<4;j++) {
        int b = q*4+j;
        acc[b].x=fmaf(fs0[j],w0.x,acc[b].x); acc[b].y=fmaf(fs0[j],w0.y,acc[b].y);
        acc[b].x=fmaf(fs1[j],w1.x,acc[b].x); acc[b].y=fmaf(fs1[j],w1.y,acc[b].y);
        acc[b].x=fmaf(fs2[j],w2.x,acc[b].x); acc[b].y=fmaf(fs2[j],w2.y,acc[b].y);
        acc[b].x=fmaf(fs3[j],w3.x,acc[b].x); acc[b].y=fmaf(fs3[j],w3.y,acc[b].y);
      }
    }
  }
  float* p = part + (size_t)blockIdx.y*OUTSZ;
  #pragma unroll
  for (int b=0;b<16;b++) {
    f32x2 v; v.x = acc[b].x; v.y = acc[b].y;
    __builtin_nontemporal_store(v, (f32x2*)(p + b*NCOL + c0));
  }
}

// out = sum_s part[s] + bias (unchanged)
__global__ void k_reduce(const float* __restrict__ part, const float* __restrict__ bias,
                         float* __restrict__ out) {
  int idx = blockIdx.x*256 + threadIdx.x;
  float acc = bias[idx % NCOL];
  #pragma unroll 8
  for (int s=0;s<KS;s++)
    acc += __builtin_nontemporal_load(part + (size_t)s*OUTSZ + idx);
  out[idx] = acc;
}

extern "C" void kernel_launch(void* const* d_in, const int* in_sizes, int n_in,
                              void* d_out, int out_size, void* d_ws, size_t ws_size,
                              hipStream_t stream) {
  const float* x        = (const float*)d_in[0];
  const float* W_in     = (const float*)d_in[1];
  const float* b_in     = (const float*)d_in[2];
  const float* W_inproj = (const float*)d_in[3];
  const float* conv_w   = (const float*)d_in[4];
  const float* conv_b   = (const float*)d_in[5];
  const float* W_xproj  = (const float*)d_in[6];
  const float* W_dt     = (const float*)d_in[7];
  const float* b_dt     = (const float*)d_in[8];
  const float* A_log    = (const float*)d_in[9];
  const float* Dp       = (const float*)d_in[10];
  const float* W_out    = (const float*)d_in[11];
  const float* W_outproj= (const float*)d_in[12];
  const float* b_outproj= (const float*)d_in[13];
  float* out = (float*)d_out;
  float* ws  = (float*)d_ws;

  float* u    = ws;             // 2097152
  float* z    = ws + 2097152;   // 2097152
  float* xdbc = ws + 4194304;   // 327680
  float* Hc   = ws + 4521984;   // 4194304
  float* Sdt  = ws + 8716288;   // 262144
  float* Hst  = ws + 8978432;   // 4194304
  float* mo   = ws + 13172736;  // 1048576
  float* part = ws + 14221312;  // 6291456
  float* Wc   = ws + 20512768;  // 16896 -> total ~82.1 MB

  k_comb  <<<66,   256, 0, stream>>>(W_in, b_in, W_inproj, Wc);
  k_mega1 <<<512,  256, 0, stream>>>(x, Wc, conv_w, conv_b,
                                     W_xproj, W_dt, b_dt, A_log,
                                     u, z, xdbc, Hc, Sdt);
  k_scan2 <<<256,  256, 0, stream>>>(A_log, Hc, Sdt, Hst);
  k_scan3 <<<512,  256, 0, stream>>>(u, z, xdbc, W_dt, b_dt, A_log, Dp, Hst, W_out, mo);
  k_final <<<dim3(6, KS), 256, 0, stream>>>(mo, W_outproj, part);
  k_reduce<<<192,  256, 0, stream>>>(part, b_outproj, out);
}